// Round 1
// baseline (929.436 us; speedup 1.0000x reference)
//
#include <hip/hip_runtime.h>
#include <stdint.h>

#define NCn 4096
#define NPn 8192
#define Hn  128
#define En  500000
#define ELn 500000

typedef unsigned short u16;
using f32x4  = __attribute__((ext_vector_type(4))) float;
using bf16x8 = __attribute__((ext_vector_type(8))) short;

__device__ inline u16 f2bf(float f) {
  union { float f; uint32_t u; } v; v.f = f;
  uint32_t r = v.u + 0x7fffu + ((v.u >> 16) & 1u);   // RNE
  return (u16)(r >> 16);
}

// ---------------------------------------------------------------------------
// Weight transpose+convert: W[K][128] fp32 -> WT[128][K] bf16
// ---------------------------------------------------------------------------
__global__ __launch_bounds__(256) void wtrans(const float* __restrict__ W,
                                              u16* __restrict__ WT, int K) {
  int t = blockIdx.x * 256 + threadIdx.x;
  int kc8 = K >> 3;
  if (t >= 128 * kc8) return;
  int kc = t % kc8, n = t / kc8;
  u16 pk[8];
#pragma unroll
  for (int j = 0; j < 8; ++j) pk[j] = f2bf(W[(size_t)(kc * 8 + j) * 128 + n]);
  uint4 v;
  v.x = (uint32_t)pk[0] | ((uint32_t)pk[1] << 16);
  v.y = (uint32_t)pk[2] | ((uint32_t)pk[3] << 16);
  v.z = (uint32_t)pk[4] | ((uint32_t)pk[5] << 16);
  v.w = (uint32_t)pk[6] | ((uint32_t)pk[7] << 16);
  *(uint4*)&WT[(size_t)n * K + kc * 8] = v;
}

// ---------------------------------------------------------------------------
// CSR build: count -> exclusive scan -> fill
// ---------------------------------------------------------------------------
__global__ __launch_bounds__(256) void count_deg(const int* __restrict__ esrc,
                                                 const int* __restrict__ edst,
                                                 int* __restrict__ cntC,
                                                 int* __restrict__ cntP) {
  int i = blockIdx.x * 256 + threadIdx.x;
  if (i >= En) return;
  atomicAdd(&cntP[edst[i]], 1);
  atomicAdd(&cntC[esrc[i]], 1);
}

__global__ __launch_bounds__(256) void scan_excl(const int* __restrict__ cnt,
                                                 int* __restrict__ off,
                                                 int* __restrict__ cur, int n) {
  __shared__ int sh[257];
  int t = threadIdx.x;
  int chunk = n >> 8;
  int base = t * chunk;
  int s = 0;
  for (int i = 0; i < chunk; ++i) s += cnt[base + i];
  sh[t] = s;
  __syncthreads();
  if (t == 0) {
    int run = 0;
    for (int i = 0; i < 256; ++i) { int v = sh[i]; sh[i] = run; run += v; }
    sh[256] = run;
  }
  __syncthreads();
  int p = sh[t];
  for (int i = 0; i < chunk; ++i) {
    off[base + i] = p; cur[base + i] = p; p += cnt[base + i];
  }
  if (t == 255) off[n] = sh[256];
}

__global__ __launch_bounds__(256) void fill_adj(const int* __restrict__ esrc,
                                                const int* __restrict__ edst,
                                                int* __restrict__ curC,
                                                int* __restrict__ curP,
                                                int* __restrict__ adjC,
                                                int* __restrict__ adjP) {
  int i = blockIdx.x * 256 + threadIdx.x;
  if (i >= En) return;
  int s = esrc[i], d = edst[i];
  int p = atomicAdd(&curP[d], 1);
  adjP[p] = s;
  int q = atomicAdd(&curC[s], 1);
  adjC[q] = d;
}

// ---------------------------------------------------------------------------
// Big projection GEMM: out[M][128] = A[M][K]fp32 @ W (as WT[128][K] bf16)
//                      + bias[128] + addend[M][128]
// BM=32, BN=128(full), BK=64; 256 thr = 4 waves, wave w owns cols w*32..w*32+31
// bf16 MFMA 16x16x32; LDS XOR-swizzled (byte ^ ((row&7)<<4)) -> 2-way max
// ---------------------------------------------------------------------------
__global__ __launch_bounds__(256) void gemm_big(const float* __restrict__ A,
                                                const u16* __restrict__ BT,
                                                const float* __restrict__ bias,
                                                const float* __restrict__ addend,
                                                float* __restrict__ out, int K) {
  __shared__ __align__(16) u16 aL[32 * 64];    // [row][k] swizzled, 4KB
  __shared__ __align__(16) u16 bL[128 * 64];   // [n][k]   swizzled, 16KB
  const int t = threadIdx.x;
  const int wid = t >> 6, lane = t & 63;
  const int ln15 = lane & 15, lhi = lane >> 4;
  const int m0 = blockIdx.x * 32;

  f32x4 acc[2][2] = {};

  const int ar0 = t >> 4;            // A staging rows (chunk 0: 0..15, chunk 1: +16)
  const int ac4 = t & 15;            // float4 col index within 64-wide k tile

  const int nIter = K >> 6;
  float4 av[2];
#pragma unroll
  for (int i = 0; i < 2; ++i)
    av[i] = *(const float4*)&A[(size_t)(m0 + ar0 + i * 16) * K + ac4 * 4];

  for (int it = 0; it < nIter; ++it) {
    const int k0 = it << 6;
    __syncthreads();                 // prior compute done -> LDS reusable
    // ---- store A tile (fp32 regs -> bf16 LDS, swizzled) ----
#pragma unroll
    for (int i = 0; i < 2; ++i) {
      int row = ar0 + i * 16;
      int off = row * 128 + ((ac4 * 8) ^ ((row & 7) << 4));
      uint2 p;
      p.x = (uint32_t)f2bf(av[i].x) | ((uint32_t)f2bf(av[i].y) << 16);
      p.y = (uint32_t)f2bf(av[i].z) | ((uint32_t)f2bf(av[i].w) << 16);
      *(uint2*)((char*)aL + off) = p;
    }
    // ---- stage BT tile (bf16 global -> LDS, swizzled dest) ----
#pragma unroll
    for (int i = 0; i < 4; ++i) {
      int idx = t + i * 256;
      int n = idx >> 3, sl = idx & 7;
      const char* src = (const char*)BT + ((size_t)n * K + k0) * 2 + sl * 16;
      uint4 v = *(const uint4*)src;
      *(uint4*)((char*)bL + n * 128 + ((sl * 16) ^ ((n & 7) << 4))) = v;
    }
    // ---- prefetch next A tile into regs (overlaps the barrier drain) ----
    if (it + 1 < nIter) {
#pragma unroll
      for (int i = 0; i < 2; ++i)
        av[i] = *(const float4*)&A[(size_t)(m0 + ar0 + i * 16) * K + (k0 + 64) + ac4 * 4];
    }
    __syncthreads();
    // ---- compute: 2 k-substeps x 4 MFMA ----
#pragma unroll
    for (int ks = 0; ks < 2; ++ks) {
      const int kb = ks * 64 + lhi * 16;   // byte offset of this lane's 8 bf16 in k
      bf16x8 afr[2], bfr[2];
#pragma unroll
      for (int mi = 0; mi < 2; ++mi) {
        int r = mi * 16 + ln15;
        afr[mi] = *(const bf16x8*)((const char*)aL + r * 128 + (kb ^ ((r & 7) << 4)));
      }
#pragma unroll
      for (int ni = 0; ni < 2; ++ni) {
        int n = wid * 32 + ni * 16 + ln15;
        bfr[ni] = *(const bf16x8*)((const char*)bL + n * 128 + (kb ^ ((n & 7) << 4)));
      }
#pragma unroll
      for (int mi = 0; mi < 2; ++mi)
#pragma unroll
        for (int ni = 0; ni < 2; ++ni)
          acc[mi][ni] = __builtin_amdgcn_mfma_f32_16x16x32_bf16(afr[mi], bfr[ni],
                                                                acc[mi][ni], 0, 0, 0);
    }
  }
  // ---- epilogue: + bias + addend; C/D layout col=lane&15, row=(lane>>4)*4+r ----
#pragma unroll
  for (int mi = 0; mi < 2; ++mi) {
#pragma unroll
    for (int ni = 0; ni < 2; ++ni) {
      int col = wid * 32 + ni * 16 + ln15;
      float bcol = bias[col];
#pragma unroll
      for (int r = 0; r < 4; ++r) {
        int row = m0 + mi * 16 + lhi * 4 + r;
        out[(size_t)row * 128 + col] = acc[mi][ni][r] + bcol + addend[(size_t)row * 128 + col];
      }
    }
  }
}

// ---------------------------------------------------------------------------
// Small layer GEMM (fp32 SIMT, exact):
//  out[M][128] = op(A1[M][128]@Wl[128][128] + A2[M][128]@Wr[128][128] + bias)
// BM=32; 256 thr as 16x16; thread tile 2m x 8n; BK=32
// ---------------------------------------------------------------------------
template <int RELU>
__global__ __launch_bounds__(256) void gemm_layer(const float* __restrict__ A1,
                                                  const float* __restrict__ A2,
                                                  const float* __restrict__ Wl,
                                                  const float* __restrict__ Wr,
                                                  const float* __restrict__ bias,
                                                  float* __restrict__ out) {
  __shared__ float aT[32][33];
  __shared__ float wT[32][128];
  const int t = threadIdx.x;
  const int tx = t & 15, ty = t >> 4;
  const int m0 = blockIdx.x * 32;
  float acc[2][8] = {};

  for (int kc = 0; kc < 8; ++kc) {
    const float* Asrc = (kc < 4) ? A1 : A2;
    const float* Wsrc = (kc < 4) ? Wl : Wr;
    const int kb = (kc & 3) * 32;
    __syncthreads();
    {   // stage A chunk 32x32
      int row = t >> 3, c4 = t & 7;
      float4 v = *(const float4*)&Asrc[(size_t)(m0 + row) * 128 + kb + c4 * 4];
      aT[row][c4 * 4 + 0] = v.x; aT[row][c4 * 4 + 1] = v.y;
      aT[row][c4 * 4 + 2] = v.z; aT[row][c4 * 4 + 3] = v.w;
    }
#pragma unroll
    for (int i = 0; i < 4; ++i) {   // stage W chunk 32x128
      int idx = t + i * 256;
      int row = idx >> 5, c4 = idx & 31;
      float4 v = *(const float4*)&Wsrc[(size_t)(kb + row) * 128 + c4 * 4];
      *(float4*)&wT[row][c4 * 4] = v;
    }
    __syncthreads();
#pragma unroll
    for (int k = 0; k < 32; ++k) {
      float a0 = aT[ty * 2 + 0][k], a1 = aT[ty * 2 + 1][k];
      float4 w0 = *(const float4*)&wT[k][tx * 8];
      float4 w1 = *(const float4*)&wT[k][tx * 8 + 4];
      float w[8] = {w0.x, w0.y, w0.z, w0.w, w1.x, w1.y, w1.z, w1.w};
#pragma unroll
      for (int j = 0; j < 8; ++j) {
        acc[0][j] += a0 * w[j];
        acc[1][j] += a1 * w[j];
      }
    }
  }
#pragma unroll
  for (int i = 0; i < 2; ++i) {
    int row = m0 + ty * 2 + i;
    float o[8];
#pragma unroll
    for (int j = 0; j < 8; ++j) {
      float v = acc[i][j] + bias[tx * 8 + j];
      o[j] = RELU ? fmaxf(v, 0.f) : v;
    }
    float4 v0 = {o[0], o[1], o[2], o[3]}, v1 = {o[4], o[5], o[6], o[7]};
    *(float4*)&out[(size_t)row * 128 + tx * 8] = v0;
    *(float4*)&out[(size_t)row * 128 + tx * 8 + 4] = v1;
  }
}

// ---------------------------------------------------------------------------
// CSR mean aggregation: wave per dst node; lanes hold 2 of 128 cols.
// Neighbor ids cooperatively loaded 64 at a time, broadcast via shfl; loads
// batched 4-deep for MLP-level ILP.
// ---------------------------------------------------------------------------
__global__ __launch_bounds__(256) void agg_mean(const int* __restrict__ adj,
                                                const int* __restrict__ off,
                                                const float* __restrict__ X,
                                                float* __restrict__ out, int ndst) {
  int w = blockIdx.x * 4 + (threadIdx.x >> 6);
  if (w >= ndst) return;
  int lane = threadIdx.x & 63;
  int s0 = off[w], s1 = off[w + 1];
  int deg = s1 - s0;
  float a0 = 0.f, a1 = 0.f;
  for (int base = 0; base < deg; base += 64) {
    int my = base + lane;
    int sv = (my < deg) ? adj[s0 + my] : 0;
    int cnt = min(64, deg - base);
    int jj = 0;
    for (; jj + 4 <= cnt; jj += 4) {
      int n0 = __shfl(sv, jj), n1 = __shfl(sv, jj + 1);
      int n2 = __shfl(sv, jj + 2), n3 = __shfl(sv, jj + 3);
      float2 f0 = *(const float2*)&X[(size_t)n0 * 128 + lane * 2];
      float2 f1 = *(const float2*)&X[(size_t)n1 * 128 + lane * 2];
      float2 f2 = *(const float2*)&X[(size_t)n2 * 128 + lane * 2];
      float2 f3 = *(const float2*)&X[(size_t)n3 * 128 + lane * 2];
      a0 += (f0.x + f1.x) + (f2.x + f3.x);
      a1 += (f0.y + f1.y) + (f2.y + f3.y);
    }
    for (; jj < cnt; ++jj) {
      int n = __shfl(sv, jj);
      float2 f = *(const float2*)&X[(size_t)n * 128 + lane * 2];
      a0 += f.x; a1 += f.y;
    }
  }
  float inv = 1.f / (float)max(deg, 1);
  float2 r; r.x = a0 * inv; r.y = a1 * inv;
  *(float2*)&out[(size_t)w * 128 + lane * 2] = r;
}

// ---------------------------------------------------------------------------
// Edge classifier: wave per label edge, 64-lane xor reduce of 128-dim dot
// ---------------------------------------------------------------------------
__global__ __launch_bounds__(256) void edge_dot(const int* __restrict__ ls,
                                                const int* __restrict__ ld,
                                                const float* __restrict__ hc2,
                                                const float* __restrict__ hp2,
                                                float* __restrict__ o, int n) {
  int w = blockIdx.x * 4 + (threadIdx.x >> 6);
  if (w >= n) return;
  int lane = threadIdx.x & 63;
  int s = ls[w], d = ld[w];
  float2 a = *(const float2*)&hc2[(size_t)s * 128 + lane * 2];
  float2 b = *(const float2*)&hp2[(size_t)d * 128 + lane * 2];
  float p = a.x * b.x + a.y * b.y;
#pragma unroll
  for (int m = 32; m; m >>= 1) p += __shfl_xor(p, m);
  if (lane == 0) o[w] = p;
}

// ---------------------------------------------------------------------------
extern "C" void kernel_launch(void* const* d_in, const int* in_sizes, int n_in,
                              void* d_out, int out_size, void* d_ws, size_t ws_size,
                              hipStream_t stream) {
  const float* x_c    = (const float*)d_in[0];
  const float* x_p    = (const float*)d_in[1];
  const float* Wc     = (const float*)d_in[2];
  const float* bc     = (const float*)d_in[3];
  const float* Wp     = (const float*)d_in[4];
  const float* bp     = (const float*)d_in[5];
  const float* emb_c  = (const float*)d_in[6];
  const float* emb_p  = (const float*)d_in[7];
  const float* W1ep_l = (const float*)d_in[8];
  const float* b1ep   = (const float*)d_in[9];
  const float* W1ep_r = (const float*)d_in[10];
  const float* W1pc_l = (const float*)d_in[11];
  const float* b1pc   = (const float*)d_in[12];
  const float* W1pc_r = (const float*)d_in[13];
  const float* W2ep_l = (const float*)d_in[14];
  const float* b2ep   = (const float*)d_in[15];
  const float* W2ep_r = (const float*)d_in[16];
  const float* W2pc_l = (const float*)d_in[17];
  const float* b2pc   = (const float*)d_in[18];
  const float* W2pc_r = (const float*)d_in[19];
  const int* e_src    = (const int*)d_in[22];
  const int* e_dst    = (const int*)d_in[23];
  const int* l_src    = (const int*)d_in[24];
  const int* l_dst    = (const int*)d_in[25];

  size_t off = 0;
  auto alloc = [&](size_t bytes) -> void* {
    void* p = (char*)d_ws + off;
    off += (bytes + 255) & ~(size_t)255;
    return p;
  };
  float* xc   = (float*)alloc((size_t)NCn * Hn * 4);
  float* xp   = (float*)alloc((size_t)NPn * Hn * 4);
  float* aggP = (float*)alloc((size_t)NPn * Hn * 4);
  float* aggC = (float*)alloc((size_t)NCn * Hn * 4);
  float* hp   = (float*)alloc((size_t)NPn * Hn * 4);
  float* hc   = (float*)alloc((size_t)NCn * Hn * 4);
  float* hp2  = (float*)alloc((size_t)NPn * Hn * 4);
  float* hc2  = (float*)alloc((size_t)NCn * Hn * 4);
  u16*   WcT  = (u16*)alloc((size_t)Hn * NCn * 2);
  u16*   WpT  = (u16*)alloc((size_t)Hn * NPn * 2);
  int*   adjP = (int*)alloc((size_t)En * 4);
  int*   adjC = (int*)alloc((size_t)En * 4);
  int*   offP = (int*)alloc((size_t)(NPn + 1) * 4);
  int*   offC = (int*)alloc((size_t)(NCn + 1) * 4);
  int*   curP = (int*)alloc((size_t)NPn * 4);
  int*   curC = (int*)alloc((size_t)NCn * 4);
  int*   cnts = (int*)alloc((size_t)(NPn + NCn) * 4);
  int*   cntP = cnts;
  int*   cntC = cnts + NPn;

  hipMemsetAsync(cnts, 0, (size_t)(NPn + NCn) * 4, stream);

  wtrans<<<(128 * (NCn >> 3) + 255) / 256, 256, 0, stream>>>(Wc, WcT, NCn);
  wtrans<<<(128 * (NPn >> 3) + 255) / 256, 256, 0, stream>>>(Wp, WpT, NPn);

  count_deg<<<(En + 255) / 256, 256, 0, stream>>>(e_src, e_dst, cntC, cntP);
  scan_excl<<<1, 256, 0, stream>>>(cntP, offP, curP, NPn);
  scan_excl<<<1, 256, 0, stream>>>(cntC, offC, curC, NCn);
  fill_adj<<<(En + 255) / 256, 256, 0, stream>>>(e_src, e_dst, curC, curP, adjC, adjP);

  gemm_big<<<NCn / 32, 256, 0, stream>>>(x_c, WcT, bc, emb_c, xc, NCn);
  gemm_big<<<NPn / 32, 256, 0, stream>>>(x_p, WpT, bp, emb_p, xp, NPn);

  agg_mean<<<NPn / 4, 256, 0, stream>>>(adjP, offP, xc, aggP, NPn);
  agg_mean<<<NCn / 4, 256, 0, stream>>>(adjC, offC, xp, aggC, NCn);
  gemm_layer<1><<<NPn / 32, 256, 0, stream>>>(aggP, xp, W1ep_l, W1ep_r, b1ep, hp);
  gemm_layer<1><<<NCn / 32, 256, 0, stream>>>(aggC, xc, W1pc_l, W1pc_r, b1pc, hc);

  agg_mean<<<NPn / 4, 256, 0, stream>>>(adjP, offP, hc, aggP, NPn);
  agg_mean<<<NCn / 4, 256, 0, stream>>>(adjC, offC, hp, aggC, NCn);
  gemm_layer<0><<<NPn / 32, 256, 0, stream>>>(aggP, hp, W2ep_l, W2ep_r, b2ep, hp2);
  gemm_layer<0><<<NCn / 32, 256, 0, stream>>>(aggC, hc, W2pc_l, W2pc_r, b2pc, hc2);

  edge_dot<<<(ELn + 3) / 4, 256, 0, stream>>>(l_src, l_dst, hc2, hp2, (float*)d_out, ELn);
}